// Round 16
// baseline (1242.462 us; speedup 1.0000x reference)
//
#include <hip/hip_runtime.h>

// Viterbi detector, bit-exact vs f32 reference.
// R16 DIAGNOSTIC HYBRID: R15's in-forward decision machinery runs and
// writes bits/map, then the PROVEN R13 k_replay compares its own values
// against them (mismatch counts -> flag[0]=main, flag[1]=tail) and
// OVERWRITES bits/map -> output is guaranteed correct. k_spin converts
// the mismatch class into extra latency (the only debug channel):
//   dur ~ base + log2(cnt)*unit + (tail?big).
// Also: wg_barrier hardened to a single asm block (lgkmcnt+s_barrier
// fused) to exclude compiler code-motion between wait and barrier.

#define DEV static __device__ __forceinline__

static constexpr int T_OUT = 16384;   // output bits per seq
static constexpr int TT    = 16388;   // T + MEM steps
static constexpr int BB    = 256;     // batch
static constexpr int CHUNK = 64;
static constexpr int NFULL = 256;     // full 64-step chunks
static constexpr int NC    = 257;     // + 4-step tail chunk
static constexpr int CROW  = 68;      // cost row stride in floats

// inverse labelings, nibble-packed: lane = (IPI_TAB[phi] >> (4*s)) & 15
static constexpr unsigned long long IPI_TAB[4] = {
  0x4b5a6978c3d2e1f0ULL,   // pi_0^-1
  0x4cb35da26e917f80ULL,   // pi_1^-1
  0x46ceb93157dfa820ULL,   // pi_2^-1
  0x4567cdefba983210ULL,   // pi_3^-1
};

DEV int pi_of(int phi, int l){
  int l0=l&1, l1=(l>>1)&1, l2=(l>>2)&1, l3=(l>>3)&1;
  switch(phi & 3){
    case 0:  return (l2)      | ((l2^l0)<<1) | ((l2^l1)<<2) | ((l3^l2)<<3);
    case 1:  return (l3^l2)   | ((l2)<<1)    | ((l2^l0)<<2) | ((l2^l1)<<3);
    case 2:  return (l2^l1)   | ((l3^l2)<<1) | ((l2)<<2)    | ((l2^l0)<<3);
    default: return (l2^l0)   | ((l2^l1)<<1) | ((l3^l2)<<2) | ((l2)<<3);
  }
}

template<int CTRL>
DEV float dppmov(float x){
  return __int_as_float(__builtin_amdgcn_update_dpp(0, __float_as_int(x), CTRL, 0xF, 0xF, true));
}

// partner exchange per phase: masks 8, 2, 1, 15 (all single DPP)
template<int PH>
DEV float partner_of(float p){
  if constexpr (PH == 0) return dppmov<0x128>(p);   // row_ror:8      -> ^8
  else if constexpr (PH == 1) return dppmov<0x4E>(p);    // quad[2,3,0,1] -> ^2
  else if constexpr (PH == 2) return dppmov<0xB1>(p);    // quad[1,0,3,2] -> ^1
  else return dppmov<0x140>(p);                          // row_mirror    -> ^15
}

// expected[s] = sum_j (1-2*bit_j(s)) * h[j], sequential f32 accumulation
DEV float exp_of_state(int s, float h0, float h1, float h2, float h3){
  float e =            ((s     ) & 1) ? -h0 : h0;
  e = __fadd_rn(e, (((s >> 1)) & 1) ? -h1 : h1);
  e = __fadd_rn(e, (((s >> 2)) & 1) ? -h2 : h2);
  e = __fadd_rn(e, (((s >> 3)) & 1) ? -h3 : h3);
  return e;
}

// async global->LDS, 16B per lane; no destination VGPRs, tracked by vmcnt.
DEV void gload_lds16(const float* g, float* l){
  __builtin_amdgcn_global_load_lds(
      (const __attribute__((address_space(1))) void*)(g),
      (__attribute__((address_space(3))) void*)(l), 16, 0, 0);
}

// HARDENED barrier: wait + barrier in ONE asm block (no code motion
// between them possible; memory clobber fences both sides).
DEV void wg_barrier(){
  asm volatile("s_waitcnt lgkmcnt(0)\n\ts_barrier" ::: "memory");
}

DEV int sel4(int k, int a, int b, int c, int d){
  return k == 0 ? a : (k == 1 ? b : (k == 2 ? c : d));
}

// decisions + in-register traceback for step range [JLO,JHI) of one chunk.
template<int JLO, int JHI>
DEV void decide_range(const float* base, const float* prev63, int sh, int e,
                      int L00,int L01,int L02,int L03,
                      int L10,int L11,int L12,int L13,
                      unsigned long long* hbD, unsigned char* hmD, int lane){
  constexpr int NW = (JHI - JLO + 1) / 2;
  unsigned msk[NW];
  #pragma unroll
  for (int i = 0; i < NW; ++i) msk[i] = 0u;
  #pragma unroll
  for (int j = JLO; j < JHI; ++j){
    const float* rp = (j == 0) ? prev63 : (base + (j - 1) * 64);
    const int l0 = sel4(j & 3, L00, L01, L02, L03);
    const int l1 = sel4(j & 3, L10, L11, L12, L13);
    float c0 = rp[sh + l0];
    float c1 = rp[sh + l1];
    unsigned long long bal = __ballot(c1 < c0);
    unsigned m16 = (unsigned)(bal >> sh) & 0xffffu;
    msk[(j - JLO) >> 1] |= m16 << (((j - JLO) & 1) << 4);
  }
  int s = e;
  unsigned long long pb = 0ull;
  #pragma unroll
  for (int j = JHI - 1; j >= JLO; --j){
    unsigned m16 = (msk[(j - JLO) >> 1] >> (((j - JLO) & 1) << 4)) & 0xffffu;
    unsigned long long b = (unsigned long long)((m16 >> s) & 1u);
    pb |= b << j;
    s = (s >> 1) | ((int)b << 3);
  }
  hbD[lane] = pb;
  hmD[lane] = (unsigned char)s;
}

// compose the 3 per-wave partials of chunk cc2 -> global bits[] + map[]
DEV void do_compose(int cc2, int sh, int e, int s4, int blk,
                    const unsigned long long* hbS, const unsigned char* hmS,
                    unsigned long long* bits, unsigned char* map){
  int sA = hmS[2*64 + sh + e];
  unsigned long long pb = hbS[2*64 + sh + e];
  int sB = hmS[1*64 + sh + sA];
  pb |= hbS[1*64 + sh + sA];
  int sC = hmS[0*64 + sh + sB];
  pb |= hbS[0*64 + sh + sB];
  const size_t pair = (size_t)cc2 * BB + blk * 4 + s4;
  bits[pair * 16 + e] = pb;
  map [pair * 16 + e] = (unsigned char)sC;
}

// ---------------- K0: zero the diff flags ----------------
__global__ void k_zero(unsigned* __restrict__ f){ f[0] = 0u; f[1] = 0u; }

// ---------------- K1: forward + in-kernel decisions + ckpt ----------------
__global__ __launch_bounds__(384, 1) void k_forward(const float* __restrict__ y,
                                                    const float* __restrict__ h,
                                                    unsigned long long* __restrict__ bits,
                                                    unsigned char* __restrict__ map,
                                                    float* __restrict__ ckpt){
  __shared__ float ring[8][256];          //  8 KB: y staging
  __shared__ float costb[2][64 * CROW];   // 34 KB: pre-squared costs, dbuf
  __shared__ float ph[3][64 * 64];        // 48 KB: p-history, triple buffer
  __shared__ unsigned long long hb[2][3][64];  // 3 KB: partial path bits
  __shared__ unsigned char hm[2][3][64];       // 384B: partial maps

  const int tid  = threadIdx.x;
  const int wv   = tid >> 6;
  const int lane = tid & 63;
  const int blk  = blockIdx.x;

  if (wv == 0){
    // ================= consumer: serial chain + p export + ckpt ============
    const int l16 = lane & 15, s4 = lane >> 4;
    const int row = l16 * 4 + s4;
    const int st0 = pi_of(0, l16);
    ph[2][63 * 64 + lane] = 0.0f;        // p(-1) = zeros for chunk 0, j=0
    float4 qa[16], ra[16];
    float p = 0.0f;

    wg_barrier();                         // B0: rings primed
    wg_barrier();                         // B1: chunk-0 costs ready
    {
      const float* cb = &costb[0][0];
      #pragma unroll
      for (int g = 0; g < 16; ++g) qa[g] = *(const float4*)(cb + row * CROW + 4 * g);
    }
    wg_barrier();                         // B2: chunk-1 costs ready

    #define CSTEP(PH, M, J, DST) \
      p = __fadd_rn(fminf(p, partner_of<PH>(p)), (M)); (DST)[(J) * 64] = p;

    for (int k = 0; k < NFULL; k += 2){
      { // period k: consume qa (chunk k), prefetch ra (chunk k+1)
        const float* cb = &costb[1][0];
        #pragma unroll
        for (int g = 0; g < 16; ++g) ra[g] = *(const float4*)(cb + row * CROW + 4 * g);
        __builtin_amdgcn_sched_barrier(0);
        float* dst = &ph[k % 3][0] + lane;
        #pragma unroll
        for (int g = 0; g < 16; ++g){
          CSTEP(0, qa[g].x, 4*g + 0, dst);
          CSTEP(1, qa[g].y, 4*g + 1, dst);
          CSTEP(2, qa[g].z, 4*g + 2, dst);
          CSTEP(3, qa[g].w, 4*g + 3, dst);
        }
        ckpt[((size_t)k * BB + blk * 4 + s4) * 16 + st0] = p;   // chunk-k ckpt
        wg_barrier();
      }
      { // period k+1: consume ra (chunk k+1), prefetch qa (chunk k+2)
        const float* cb = &costb[0][0];
        #pragma unroll
        for (int g = 0; g < 16; ++g) qa[g] = *(const float4*)(cb + row * CROW + 4 * g);
        __builtin_amdgcn_sched_barrier(0);
        float* dst = &ph[(k + 1) % 3][0] + lane;
        #pragma unroll
        for (int g = 0; g < 16; ++g){
          CSTEP(0, ra[g].x, 4*g + 0, dst);
          CSTEP(1, ra[g].y, 4*g + 1, dst);
          CSTEP(2, ra[g].z, 4*g + 2, dst);
          CSTEP(3, ra[g].w, 4*g + 3, dst);
        }
        ckpt[((size_t)(k + 1) * BB + blk * 4 + s4) * 16 + st0] = p;
        wg_barrier();
      }
    }
    { // E1: tail chunk (4 steps), costs computed inline
      const float h0 = h[0], h1 = h[1], h2 = h[2], h3 = h[3];
      const float EA = exp_of_state(pi_of(1, l16), h0, h1, h2, h3);
      const float EB = exp_of_state(pi_of(2, l16), h0, h1, h2, h3);
      const float EC = exp_of_state(pi_of(3, l16), h0, h1, h2, h3);
      const float ED = exp_of_state(pi_of(0, l16), h0, h1, h2, h3);
      const float4 yv = *(const float4*)(y + (size_t)(blk * 4 + s4) * TT + (size_t)NFULL * CHUNK);
      float* dst = &ph[1][0] + lane;     // 256 % 3 == 1
      float dd;
      dd = __fsub_rn(yv.x, EA); CSTEP(0, __fmul_rn(dd, dd), 0, dst);
      dd = __fsub_rn(yv.y, EB); CSTEP(1, __fmul_rn(dd, dd), 1, dst);
      dd = __fsub_rn(yv.z, EC); CSTEP(2, __fmul_rn(dd, dd), 2, dst);
      dd = __fsub_rn(yv.w, ED); CSTEP(3, __fmul_rn(dd, dd), 3, dst);
    }
    #undef CSTEP
    wg_barrier();                         // E1 barrier
  } else if (wv <= 2){
    // ================= producers: costs 2 chunks ahead =================
    const int gbase = (wv - 1) * 8;
    const int pl16  = lane >> 2;
    const int ps4   = lane & 3;
    const float h0 = h[0], h1 = h[1], h2 = h[2], h3 = h[3];
    const float EA = exp_of_state(pi_of(1, pl16), h0, h1, h2, h3);
    const float EB = exp_of_state(pi_of(2, pl16), h0, h1, h2, h3);
    const float EC = exp_of_state(pi_of(3, pl16), h0, h1, h2, h3);
    const float ED = exp_of_state(pi_of(0, pl16), h0, h1, h2, h3);
    const float* ysrc = y + (size_t)(blk * 4 + ps4) * TT + pl16 * 4;

    #define PRODUCE(RB, CB)                                                   \
      {                                                                       \
        const float* rb_ = (RB);                                              \
        float* cb_ = (CB);                                                    \
        _Pragma("unroll")                                                     \
        for (int g2 = 0; g2 < 8; ++g2){                                       \
          const int g = gbase + g2;                                           \
          float4 yv = *(const float4*)(rb_ + g * 16 + ps4 * 4);               \
          float4 c; float d_;                                                 \
          d_ = __fsub_rn(yv.x, EA); c.x = __fmul_rn(d_, d_);                  \
          d_ = __fsub_rn(yv.y, EB); c.y = __fmul_rn(d_, d_);                  \
          d_ = __fsub_rn(yv.z, EC); c.z = __fmul_rn(d_, d_);                  \
          d_ = __fsub_rn(yv.w, ED); c.w = __fmul_rn(d_, d_);                  \
          *(float4*)(cb_ + lane * CROW + 4 * g) = c;                          \
        }                                                                     \
      }

    if (wv == 1){
      #pragma unroll
      for (int q = 0; q < 8; ++q)
        gload_lds16(ysrc + q * CHUNK, &ring[q][0]);
      asm volatile("s_waitcnt vmcnt(6)" ::: "memory");
    }
    wg_barrier();                         // B0
    PRODUCE(&ring[0][0], &costb[0][0]);
    wg_barrier();                         // B1
    PRODUCE(&ring[1][0], &costb[1][0]);
    if (wv == 1){
      gload_lds16(ysrc + 8 * CHUNK, &ring[0][0]);
      asm volatile("s_waitcnt vmcnt(6)" ::: "memory");
    }
    wg_barrier();                         // B2

    for (int k = 0; k < NFULL; k += 2){
      if (k + 2 < NFULL) PRODUCE(&ring[(k + 2) & 7][0], &costb[0][0]);
      if (wv == 1){
        const int ci = (k + 9 < NFULL) ? k + 9 : NFULL - 1;
        gload_lds16(ysrc + ci * CHUNK, &ring[(k + 9) & 7][0]);
        asm volatile("s_waitcnt vmcnt(6)" ::: "memory");
      }
      wg_barrier();
      if (k + 3 < NFULL) PRODUCE(&ring[(k + 3) & 7][0], &costb[1][0]);
      if (wv == 1){
        const int ci = (k + 10 < NFULL) ? k + 10 : NFULL - 1;
        gload_lds16(ysrc + ci * CHUNK, &ring[(k + 10) & 7][0]);
        asm volatile("s_waitcnt vmcnt(6)" ::: "memory");
      }
      wg_barrier();
    }
    #undef PRODUCE
    wg_barrier();                         // E1 barrier
  } else {
    // ================= decision waves (trail consumer by 1 chunk) ============
    const int d  = wv - 3;                // 0: j 0-15 (+compose), 1: 16-39, 2: 40-63
    const int s4 = lane >> 4, e = lane & 15;
    const int sh = s4 * 16;
    int L00, L01, L02, L03, L10, L11, L12, L13;
    {
      const int k0 = e >> 1;
      L00 = (int)((IPI_TAB[0] >> (4 * k0)) & 15);
      L01 = (int)((IPI_TAB[1] >> (4 * k0)) & 15);
      L02 = (int)((IPI_TAB[2] >> (4 * k0)) & 15);
      L03 = (int)((IPI_TAB[3] >> (4 * k0)) & 15);
      L10 = (int)((IPI_TAB[0] >> (4 * (k0 + 8))) & 15);
      L11 = (int)((IPI_TAB[1] >> (4 * (k0 + 8))) & 15);
      L12 = (int)((IPI_TAB[2] >> (4 * (k0 + 8))) & 15);
      L13 = (int)((IPI_TAB[3] >> (4 * (k0 + 8))) & 15);
    }
    wg_barrier(); wg_barrier(); wg_barrier();   // B0, B1, B2

    for (int c = 0; c < NFULL; ++c){
      if (d == 0 && c >= 2)
        do_compose(c - 2, sh, e, s4, blk,
                   &hb[(c - 2) & 1][0][0], &hm[(c - 2) & 1][0][0], bits, map);
      if (c >= 1){
        const int cc = c - 1;
        const float* base   = &ph[cc % 3][0];
        const float* prev63 = &ph[(cc + 2) % 3][0] + 63 * 64;
        unsigned long long* hbD = &hb[cc & 1][d][0];
        unsigned char*      hmD = &hm[cc & 1][d][0];
        if (d == 0)      decide_range< 0, 16>(base, prev63, sh, e, L00,L01,L02,L03, L10,L11,L12,L13, hbD, hmD, lane);
        else if (d == 1) decide_range<16, 40>(base, prev63, sh, e, L00,L01,L02,L03, L10,L11,L12,L13, hbD, hmD, lane);
        else             decide_range<40, 64>(base, prev63, sh, e, L00,L01,L02,L03, L10,L11,L12,L13, hbD, hmD, lane);
      }
      wg_barrier();
    }
    { // E1: decisions for chunk 255; w3 composes chunk 254
      if (d == 0)
        do_compose(254, sh, e, s4, blk, &hb[0][0][0], &hm[0][0][0], bits, map);
      const int cc = 255;
      const float* base   = &ph[cc % 3][0];                  // ph[0]
      const float* prev63 = &ph[(cc + 2) % 3][0] + 63 * 64;  // ph[2] (chunk 254)
      unsigned long long* hbD = &hb[1][d][0];
      unsigned char*      hmD = &hm[1][d][0];
      if (d == 0)      decide_range< 0, 16>(base, prev63, sh, e, L00,L01,L02,L03, L10,L11,L12,L13, hbD, hmD, lane);
      else if (d == 1) decide_range<16, 40>(base, prev63, sh, e, L00,L01,L02,L03, L10,L11,L12,L13, hbD, hmD, lane);
      else             decide_range<40, 64>(base, prev63, sh, e, L00,L01,L02,L03, L10,L11,L12,L13, hbD, hmD, lane);
    }
    wg_barrier();                         // E1 barrier
    if (d == 0){
      // E2: compose chunk 255; tail chunk (4 steps) -> map only
      do_compose(255, sh, e, s4, blk, &hb[1][0][0], &hm[1][0][0], bits, map);
      unsigned m16s[4];
      #pragma unroll
      for (int j = 0; j < 4; ++j){
        const float* rp = (j == 0) ? (&ph[0][0] + 63 * 64) : (&ph[1][0] + (j - 1) * 64);
        const int l0 = sel4(j & 3, L00, L01, L02, L03);
        const int l1 = sel4(j & 3, L10, L11, L12, L13);
        float c0 = rp[sh + l0];
        float c1 = rp[sh + l1];
        unsigned long long bal = __ballot(c1 < c0);
        m16s[j] = (unsigned)(bal >> sh) & 0xffffu;
      }
      int s = e;
      #pragma unroll
      for (int j = 3; j >= 0; --j){
        unsigned b = (m16s[j] >> s) & 1u;
        s = (s >> 1) | ((int)b << 3);
      }
      map[((size_t)NFULL * BB + blk * 4 + s4) * 16 + e] = (unsigned char)s;
    }
  }
}

// ---------------- K2: PROVEN replay -> diff-count + overwrite bits/map ------
// role = (in-state bit3) per phase; decision d = strict (cand_b1 < cand_b0).
template<int PH>
DEV unsigned rstep(float& p, float yv, float E, bool role){
  float partner = partner_of<PH>(p);
  float c1 = role ? p : partner;
  float c0 = role ? partner : p;
  unsigned d = (c1 < c0) ? 1u : 0u;
  float mn = fminf(p, partner);
  float dd = __fsub_rn(yv, E);
  p = __fadd_rn(mn, __fmul_rn(dd, dd));
  return d;
}

__global__ __launch_bounds__(256) void k_replay(const float* __restrict__ y,
                                                const float* __restrict__ h,
                                                const float* __restrict__ ckpt,
                                                unsigned long long* __restrict__ bits,
                                                unsigned char* __restrict__ map,
                                                unsigned* __restrict__ flag){
  const int gt   = blockIdx.x * 256 + threadIdx.x;
  const int pair = gt >> 4;              // c*256 + seq
  const int l16  = gt & 15;
  const int c    = pair >> 8;
  const int seq  = pair & 255;
  const float h0 = h[0], h1 = h[1], h2 = h[2], h3 = h[3];
  const float EA = exp_of_state(pi_of(1,l16), h0,h1,h2,h3);
  const float EB = exp_of_state(pi_of(2,l16), h0,h1,h2,h3);
  const float EC = exp_of_state(pi_of(3,l16), h0,h1,h2,h3);
  const float ED = exp_of_state(pi_of(0,l16), h0,h1,h2,h3);
  const bool r0 = (((l16>>3) ^ (l16>>2)) & 1) != 0;   // bit3 of pi_0(l)
  const bool r1 = (((l16>>2) ^ (l16>>1)) & 1) != 0;   // bit3 of pi_1(l)
  const bool r2 = (((l16>>2) ^  l16    ) & 1) != 0;   // bit3 of pi_2(l)
  const bool r3 = (( l16>>2)             & 1) != 0;   // bit3 of pi_3(l)
  const int  st0 = pi_of(0, l16);

  float p = (c == 0) ? 0.0f : ckpt[((size_t)(c - 1) * BB + seq) * 16 + st0];
  const float* yc = y + (size_t)seq * TT + c * CHUNK;
  unsigned lo = 0, hi = 0;

  if (c < NFULL){
    #pragma unroll
    for (int g = 0; g < 16; ++g){
      float4 yv = *(const float4*)(yc + 4*g);
      unsigned d0 = rstep<0>(p, yv.x, EA, r0);
      unsigned d1 = rstep<1>(p, yv.y, EB, r1);
      unsigned d2 = rstep<2>(p, yv.z, EC, r2);
      unsigned d3 = rstep<3>(p, yv.w, ED, r3);
      const int t = 4 * g;
      if (t < 32) lo |= (d0 << t) | (d1 << (t+1)) | (d2 << (t+2)) | (d3 << (t+3));
      else        hi |= (d0 << (t-32)) | (d1 << (t-31)) | (d2 << (t-30)) | (d3 << (t-29));
    }
  } else {
    float4 yv = *(const float4*)(yc);
    unsigned d0 = rstep<0>(p, yv.x, EA, r0);
    unsigned d1 = rstep<1>(p, yv.y, EB, r1);
    unsigned d2 = rstep<2>(p, yv.z, EC, r2);
    unsigned d3 = rstep<3>(p, yv.w, ED, r3);
    lo = d0 | (d1 << 1) | (d2 << 2) | (d3 << 3);
  }

  // ---- fused traceback (proven): words live in this 16-lane group's regs.
  const int base = (threadIdx.x & 63) & 48;
  int s = l16;
  unsigned long long pb = 0ull;
  if (c < NFULL){
    #pragma unroll
    for (int j = 63; j >= 0; --j){
      int l = (int)((IPI_TAB[(j + 1) & 3] >> (4 * s)) & 15);
      unsigned hw = __shfl((j >= 32) ? hi : lo, base + l);
      unsigned long long b = (hw >> (j & 31)) & 1;
      s = (s >> 1) | ((int)b << 3);
      pb |= b << j;
    }
  } else {
    #pragma unroll
    for (int j = 3; j >= 0; --j){
      int l = (int)((IPI_TAB[(j + 1) & 3] >> (4 * s)) & 15);
      unsigned hw = __shfl(lo, base + l);
      unsigned long long b = (hw >> j) & 1;
      s = (s >> 1) | ((int)b << 3);
      pb |= b << j;
    }
  }

  // ---- diff vs R15's in-forward decisions (debug channel) ----
  const unsigned long long oldb = bits[(size_t)pair * 16 + l16];
  const unsigned char      oldm = map [(size_t)pair * 16 + l16];
  const bool mmMain = (c <  NFULL) && ((oldb != pb) || (oldm != (unsigned char)s));
  const bool mmTail = (c == NFULL) && (oldm != (unsigned char)s);
  unsigned long long balA = __ballot(mmMain);
  unsigned long long balB = __ballot(mmTail);
  if ((threadIdx.x & 63) == 0){
    if (balA) atomicAdd(flag + 0, (unsigned)__popcll(balA));
    if (balB) atomicAdd(flag + 1, (unsigned)__popcll(balB));
  }

  bits[(size_t)pair * 16 + l16] = pb;      // overwrite with proven values
  map [(size_t)pair * 16 + l16] = (unsigned char)s;
}

// ---------------- K3: spin ~ f(mismatch class) — the debug channel ----------
__global__ __launch_bounds__(64) void k_spin(const unsigned* __restrict__ flag){
  const unsigned c0 = flag[0], c1 = flag[1];
  int cls = 0; { unsigned t = c0; while (t){ ++cls; t >>= 1; } }   // 0..~21
  long iters = (long)cls * 8192 + (c1 ? 131072 : 0);
  float a = 1.0f + (float)threadIdx.x;
  for (long i = 0; i < iters; ++i) a = __builtin_fmaf(a, 1.0000001f, 1e-7f);
  asm volatile("" :: "v"(a));
}

// ---------------- K4: compose maps backward -> chunk end states ----------------
__global__ __launch_bounds__(256) void k_compose(const unsigned char* __restrict__ map,
                                                 unsigned char* __restrict__ Earr){
  const int seq = threadIdx.x;
  int s = 0;
  Earr[(size_t)NFULL * BB + seq] = 0;              // end state of tail chunk = 0
  #pragma unroll 8
  for (int c = NC - 1; c >= 1; --c){
    const uint4 mr = *(const uint4*)(map + ((size_t)c * BB + seq) * 16);
    unsigned wsel = (s < 8) ? ((s < 4) ? mr.x : mr.y) : ((s < 12) ? mr.z : mr.w);
    s = (wsel >> ((s & 3) * 8)) & 15;
    Earr[(size_t)(c - 1) * BB + seq] = (unsigned char)s;
  }
}

// ---------------- K5: emit = select hypothesis, expand bits to floats --------
__global__ __launch_bounds__(256) void k_emit(const unsigned long long* __restrict__ bits,
                                              const unsigned char* __restrict__ Earr,
                                              float* __restrict__ out){
  const int gt   = blockIdx.x * 256 + threadIdx.x;
  const int pair = gt >> 4;        // c*256+seq, c < 256
  const int l16  = gt & 15;
  const int c    = pair >> 8;
  const int seq  = pair & 255;
  const int e    = Earr[(size_t)c * BB + seq];             // broadcast in group
  const unsigned long long w = bits[(size_t)pair * 16 + e];// broadcast in group
  const int j0 = l16 * 4;
  float4 f;
  f.x = (float)((w >> (j0    )) & 1);
  f.y = (float)((w >> (j0 + 1)) & 1);
  f.z = (float)((w >> (j0 + 2)) & 1);
  f.w = (float)((w >> (j0 + 3)) & 1);
  *(float4*)(out + (size_t)seq * T_OUT + c * CHUNK + j0) = f;
}

extern "C" void kernel_launch(void* const* d_in, const int* in_sizes, int n_in,
                              void* d_out, int out_size, void* d_ws, size_t ws_size,
                              hipStream_t stream){
  const float* y = (const float*)d_in[0];
  const float* h = (const float*)d_in[1];
  float* out = (float*)d_out;

  const size_t BITS_B = (size_t)NC * BB * 16 * 8;           // 8,421,376
  const size_t MAP_B  = (size_t)NC * BB * 16;               // 1,052,672
  const size_t E_B    = (size_t)NC * BB;                    //    65,792
  const size_t CKPT_B = (size_t)NFULL * BB * 16 * 4;        // 4,194,304
  const size_t FLAG_B = 128;
  if (ws_size < BITS_B + MAP_B + E_B + CKPT_B + FLAG_B) return;

  char* ws = (char*)d_ws;
  unsigned long long* bits = (unsigned long long*)ws;
  unsigned char*      map  = (unsigned char*)(ws + BITS_B);
  unsigned char*      Earr = (unsigned char*)(ws + BITS_B + MAP_B);
  float*              ckpt = (float*)(ws + BITS_B + MAP_B + E_B);
  unsigned*           flag = (unsigned*)(ws + BITS_B + MAP_B + E_B + CKPT_B);

  hipLaunchKernelGGL(k_zero,    dim3(1),    dim3(1),   0, stream, flag);
  hipLaunchKernelGGL(k_forward, dim3(64),   dim3(384), 0, stream, y, h, bits, map, ckpt);
  hipLaunchKernelGGL(k_replay,  dim3(4112), dim3(256), 0, stream, y, h, ckpt, bits, map, flag);
  hipLaunchKernelGGL(k_spin,    dim3(1),    dim3(64),  0, stream, flag);
  hipLaunchKernelGGL(k_compose, dim3(1),    dim3(256), 0, stream, map, Earr);
  hipLaunchKernelGGL(k_emit,    dim3(4096), dim3(256), 0, stream, bits, Earr, out);
}

// Round 18
// 1000.565 us; speedup vs baseline: 1.2418x; 1.2418x over previous
//
#include <hip/hip_runtime.h>

// Viterbi detector, bit-exact vs f32 reference.
// R18 = R17 with the flush-sync RACE FIXED: per-segment counters.
// R17's single counter counted global flush EVENTS (64 events != all 64
// blocks flushed segment s) -> replay could read an unpublished ckpt
// segment -> nondeterministic output (tripwire). Now each forward block
// bumps cnt[seg] (release, agent scope) after flushing segment seg, and
// replay workers wait cnt[seg]==64 before reading chunk c in segment seg.
// Blocks 0-63: R13 forward (consumer + 2 producers + idler). Blocks
// 64-511: persistent replay workers (proven R13 math).
// K4 compose maps -> chunk end states. K5 emit = pure-BW bit expansion.

#define DEV static __device__ __forceinline__

static constexpr int T_OUT = 16384;   // output bits per seq
static constexpr int TT    = 16388;   // T + MEM steps
static constexpr int BB    = 256;     // batch
static constexpr int CHUNK = 64;
static constexpr int NFULL = 256;     // full 64-step chunks
static constexpr int NC    = 257;     // + 4-step tail chunk
static constexpr int CROW  = 68;      // cost row stride in floats
static constexpr int FWD_BLOCKS = 64;
static constexpr int RPL_BLOCKS = 448;
static constexpr int NTILES = 4112;   // NC*BB*16 lanes / 256
static constexpr int NSEG   = 16;     // ckpt segments (16 chunks each)

// inverse labelings, nibble-packed: lane = (IPI_TAB[phi] >> (4*s)) & 15
static constexpr unsigned long long IPI_TAB[4] = {
  0x4b5a6978c3d2e1f0ULL,   // pi_0^-1
  0x4cb35da26e917f80ULL,   // pi_1^-1
  0x46ceb93157dfa820ULL,   // pi_2^-1
  0x4567cdefba983210ULL,   // pi_3^-1
};

DEV int pi_of(int phi, int l){
  int l0=l&1, l1=(l>>1)&1, l2=(l>>2)&1, l3=(l>>3)&1;
  switch(phi & 3){
    case 0:  return (l2)      | ((l2^l0)<<1) | ((l2^l1)<<2) | ((l3^l2)<<3);
    case 1:  return (l3^l2)   | ((l2)<<1)    | ((l2^l0)<<2) | ((l2^l1)<<3);
    case 2:  return (l2^l1)   | ((l3^l2)<<1) | ((l2)<<2)    | ((l2^l0)<<3);
    default: return (l2^l0)   | ((l2^l1)<<1) | ((l3^l2)<<2) | ((l2)<<3);
  }
}

template<int CTRL>
DEV float dppmov(float x){
  return __int_as_float(__builtin_amdgcn_update_dpp(0, __float_as_int(x), CTRL, 0xF, 0xF, true));
}

// partner exchange per phase: masks 8, 2, 1, 15 (all single DPP)
template<int PH>
DEV float partner_of(float p){
  if constexpr (PH == 0) return dppmov<0x128>(p);   // row_ror:8      -> ^8
  else if constexpr (PH == 1) return dppmov<0x4E>(p);    // quad[2,3,0,1] -> ^2
  else if constexpr (PH == 2) return dppmov<0xB1>(p);    // quad[1,0,3,2] -> ^1
  else return dppmov<0x140>(p);                          // row_mirror    -> ^15
}

// expected[s] = sum_j (1-2*bit_j(s)) * h[j], sequential f32 accumulation
DEV float exp_of_state(int s, float h0, float h1, float h2, float h3){
  float e =            ((s     ) & 1) ? -h0 : h0;
  e = __fadd_rn(e, (((s >> 1)) & 1) ? -h1 : h1);
  e = __fadd_rn(e, (((s >> 2)) & 1) ? -h2 : h2);
  e = __fadd_rn(e, (((s >> 3)) & 1) ? -h3 : h3);
  return e;
}

// 8 chain steps, costs PRE-SQUARED: p = min(p, dpp_ph(p)) + m_i. (R13 proven)
DEV void chain8(float& p, float m0, float m1, float m2, float m3,
                float m4, float m5, float m6, float m7){
  float mn;
  asm volatile(
    "v_min_f32_dpp %1, %0, %0 row_ror:8 row_mask:0xf bank_mask:0xf\n\t"
    "v_add_f32 %0, %1, %2\n\t"
    "s_nop 1\n\t"
    "v_min_f32_dpp %1, %0, %0 quad_perm:[2,3,0,1] row_mask:0xf bank_mask:0xf\n\t"
    "v_add_f32 %0, %1, %3\n\t"
    "s_nop 1\n\t"
    "v_min_f32_dpp %1, %0, %0 quad_perm:[1,0,3,2] row_mask:0xf bank_mask:0xf\n\t"
    "v_add_f32 %0, %1, %4\n\t"
    "s_nop 1\n\t"
    "v_min_f32_dpp %1, %0, %0 row_mirror row_mask:0xf bank_mask:0xf\n\t"
    "v_add_f32 %0, %1, %5\n\t"
    "s_nop 1\n\t"
    "v_min_f32_dpp %1, %0, %0 row_ror:8 row_mask:0xf bank_mask:0xf\n\t"
    "v_add_f32 %0, %1, %6\n\t"
    "s_nop 1\n\t"
    "v_min_f32_dpp %1, %0, %0 quad_perm:[2,3,0,1] row_mask:0xf bank_mask:0xf\n\t"
    "v_add_f32 %0, %1, %7\n\t"
    "s_nop 1\n\t"
    "v_min_f32_dpp %1, %0, %0 quad_perm:[1,0,3,2] row_mask:0xf bank_mask:0xf\n\t"
    "v_add_f32 %0, %1, %8\n\t"
    "s_nop 1\n\t"
    "v_min_f32_dpp %1, %0, %0 row_mirror row_mask:0xf bank_mask:0xf\n\t"
    "v_add_f32 %0, %1, %9"
    : "+v"(p), "=&v"(mn)
    : "v"(m0), "v"(m1), "v"(m2), "v"(m3),
      "v"(m4), "v"(m5), "v"(m6), "v"(m7));
}

// async global->LDS, 16B per lane; no destination VGPRs, tracked by vmcnt.
DEV void gload_lds16(const float* g, float* l){
  __builtin_amdgcn_global_load_lds(
      (const __attribute__((address_space(1))) void*)(g),
      (__attribute__((address_space(3))) void*)(l), 16, 0, 0);
}

// hardened barrier: wait+barrier fused, LDS visibility; vmcnt stays in flight.
DEV void wg_barrier(){
  asm volatile("s_waitcnt lgkmcnt(0)\n\ts_barrier" ::: "memory");
}

// one replay ACS step (R13 proven)
template<int PH>
DEV unsigned rstep(float& p, float yv, float E, bool role){
  float partner = partner_of<PH>(p);
  float c1 = role ? p : partner;
  float c0 = role ? partner : p;
  unsigned d = (c1 < c0) ? 1u : 0u;
  float mn = fminf(p, partner);
  float dd = __fsub_rn(yv, E);
  p = __fadd_rn(mn, __fmul_rn(dd, dd));
  return d;
}

// ---------------- K0: zero the per-segment counters ----------------
__global__ void k_zero(unsigned* __restrict__ c){
  for (int i = 0; i < NSEG; ++i) c[i] = 0u;
}

// ---------------- K1: fused forward + persistent replay ----------------
__global__ __launch_bounds__(256, 1) void k_main(const float* __restrict__ y,
                                                 const float* __restrict__ h,
                                                 float* __restrict__ ckpt,
                                                 unsigned long long* __restrict__ bits,
                                                 unsigned char* __restrict__ map,
                                                 unsigned* __restrict__ counter){
  __shared__ float ring[8][256];          //  8 KB: y staging
  __shared__ float costb[2][64 * CROW];   // 34 KB: pre-squared costs, dbuf
  __shared__ float cks[16 * 64];          //  4 KB: 16-chunk ckpt segment

  const int tid  = threadIdx.x;
  const int lane = tid & 63;

  if (blockIdx.x < FWD_BLOCKS){
    // ===================== FORWARD ROLE (R13) =====================
    const int wv  = tid >> 6;
    const int blk = blockIdx.x;

    if (wv == 0){
      // ---- consumer: the serial chain ----
      const int l16 = lane & 15, s4 = lane >> 4;
      const int st0 = pi_of(0, l16);
      const int row = l16 * 4 + s4;
      float4 qA[16], qB[16];
      float p = 0.0f;                     // in0 = zeros

      wg_barrier();                       // B0
      wg_barrier();                       // B1: chunk-0 costs ready
      {
        const float* cb = &costb[0][0];
        #pragma unroll
        for (int g = 0; g < 16; ++g)
          qA[g] = *(const float4*)(cb + row * CROW + 4 * g);
      }
      wg_barrier();                       // B2: chunk-1 costs ready

      #define FLUSH(SEG)                                                      \
        {                                                                     \
          const int seg_ = (SEG);                                             \
          _Pragma("unroll")                                                   \
          for (int ch = 0; ch < 16; ++ch){                                    \
            const size_t chunkIdx = (size_t)seg_ * 16 + ch;                   \
            __hip_atomic_store(&ckpt[(chunkIdx * BB + blk * 4) * 16 + lane],  \
                               cks[ch * 64 + lane],                           \
                               __ATOMIC_RELAXED, __HIP_MEMORY_SCOPE_AGENT);   \
          }                                                                   \
          asm volatile("s_waitcnt vmcnt(0)" ::: "memory");                    \
          if (lane == 0)                                                      \
            __hip_atomic_fetch_add(&counter[seg_], 1u,                        \
                                   __ATOMIC_RELEASE, __HIP_MEMORY_SCOPE_AGENT);\
        }

      for (int k = 0; k < NFULL; k += 2){
        { // period k: consume qA (chunk k), prefetch qB (chunk k+1)
          const float* cb = &costb[1][0];
          #pragma unroll
          for (int g = 0; g < 16; ++g)
            qB[g] = *(const float4*)(cb + row * CROW + 4 * g);
          __builtin_amdgcn_sched_barrier(0);
          #pragma unroll
          for (int g = 0; g < 16; g += 2)
            chain8(p, qA[g].x, qA[g].y, qA[g].z, qA[g].w,
                      qA[g+1].x, qA[g+1].y, qA[g+1].z, qA[g+1].w);
          cks[(k & 15) * 64 + s4 * 16 + st0] = p;
          wg_barrier();
        }
        { // period k+1: consume qB (chunk k+1), prefetch qA (chunk k+2)
          const float* cb = &costb[0][0];
          #pragma unroll
          for (int g = 0; g < 16; ++g)
            qA[g] = *(const float4*)(cb + row * CROW + 4 * g);
          __builtin_amdgcn_sched_barrier(0);
          #pragma unroll
          for (int g = 0; g < 16; g += 2)
            chain8(p, qB[g].x, qB[g].y, qB[g].z, qB[g].w,
                      qB[g+1].x, qB[g+1].y, qB[g+1].z, qB[g+1].w);
          cks[((k + 1) & 15) * 64 + s4 * 16 + st0] = p;
          if (((k + 1) & 15) == 15) FLUSH((k + 1) >> 4);
          wg_barrier();
        }
      }
      #undef FLUSH
    } else if (wv <= 2){
      // ---- producers: costs 2 chunks ahead (R13 verbatim) ----
      const int gbase = (wv - 1) * 8;
      const int pl16  = lane >> 2;
      const int ps4   = lane & 3;
      const float h0 = h[0], h1 = h[1], h2 = h[2], h3 = h[3];
      const float EA = exp_of_state(pi_of(1, pl16), h0, h1, h2, h3);
      const float EB = exp_of_state(pi_of(2, pl16), h0, h1, h2, h3);
      const float EC = exp_of_state(pi_of(3, pl16), h0, h1, h2, h3);
      const float ED = exp_of_state(pi_of(0, pl16), h0, h1, h2, h3);
      const float* ysrc = y + (size_t)(blk * 4 + ps4) * TT + pl16 * 4;

      #define PRODUCE(RB, CB)                                                 \
        {                                                                     \
          const float* rb_ = (RB);                                            \
          float* cb_ = (CB);                                                  \
          _Pragma("unroll")                                                   \
          for (int g2 = 0; g2 < 8; ++g2){                                     \
            const int g = gbase + g2;                                         \
            float4 yv = *(const float4*)(rb_ + g * 16 + ps4 * 4);             \
            float4 c; float d_;                                               \
            d_ = __fsub_rn(yv.x, EA); c.x = __fmul_rn(d_, d_);                \
            d_ = __fsub_rn(yv.y, EB); c.y = __fmul_rn(d_, d_);                \
            d_ = __fsub_rn(yv.z, EC); c.z = __fmul_rn(d_, d_);                \
            d_ = __fsub_rn(yv.w, ED); c.w = __fmul_rn(d_, d_);                \
            *(float4*)(cb_ + lane * CROW + 4 * g) = c;                        \
          }                                                                   \
        }

      if (wv == 1){
        #pragma unroll
        for (int q = 0; q < 8; ++q)
          gload_lds16(ysrc + q * CHUNK, &ring[q][0]);
        asm volatile("s_waitcnt vmcnt(6)" ::: "memory");
      }
      wg_barrier();                       // B0
      PRODUCE(&ring[0][0], &costb[0][0]);
      wg_barrier();                       // B1
      PRODUCE(&ring[1][0], &costb[1][0]);
      if (wv == 1){
        gload_lds16(ysrc + 8 * CHUNK, &ring[0][0]);
        asm volatile("s_waitcnt vmcnt(6)" ::: "memory");
      }
      wg_barrier();                       // B2

      for (int k = 0; k < NFULL; k += 2){
        if (k + 2 < NFULL) PRODUCE(&ring[(k + 2) & 7][0], &costb[0][0]);
        if (wv == 1){
          const int ci = (k + 9 < NFULL) ? k + 9 : NFULL - 1;
          gload_lds16(ysrc + ci * CHUNK, &ring[(k + 9) & 7][0]);
          asm volatile("s_waitcnt vmcnt(6)" ::: "memory");
        }
        wg_barrier();
        if (k + 3 < NFULL) PRODUCE(&ring[(k + 3) & 7][0], &costb[1][0]);
        if (wv == 1){
          const int ci = (k + 10 < NFULL) ? k + 10 : NFULL - 1;
          gload_lds16(ysrc + ci * CHUNK, &ring[(k + 10) & 7][0]);
          asm volatile("s_waitcnt vmcnt(6)" ::: "memory");
        }
        wg_barrier();
      }
      #undef PRODUCE
    } else {
      // ---- idler wave: participate in all 259 barriers ----
      for (int i = 0; i < 259; ++i) wg_barrier();
    }
  } else {
    // ===================== REPLAY ROLE (persistent, R13 math) =====================
    const int rb  = blockIdx.x - FWD_BLOCKS;
    const int l16 = tid & 15;
    const int sub = tid >> 4;             // pair-in-tile 0..15
    const float h0 = h[0], h1 = h[1], h2 = h[2], h3 = h[3];
    const float EA = exp_of_state(pi_of(1,l16), h0,h1,h2,h3);
    const float EB = exp_of_state(pi_of(2,l16), h0,h1,h2,h3);
    const float EC = exp_of_state(pi_of(3,l16), h0,h1,h2,h3);
    const float ED = exp_of_state(pi_of(0,l16), h0,h1,h2,h3);
    const bool r0 = (((l16>>3) ^ (l16>>2)) & 1) != 0;
    const bool r1 = (((l16>>2) ^ (l16>>1)) & 1) != 0;
    const bool r2 = (((l16>>2) ^  l16    ) & 1) != 0;
    const bool r3 = (( l16>>2)             & 1) != 0;
    const int  st0  = pi_of(0, l16);
    const int  base = lane & 48;

    for (int t = rb; t < NTILES; t += RPL_BLOCKS){
      const int pair = t * 16 + sub;
      const int c    = pair >> 8;
      const int seq  = pair & 255;

      // wait until the ckpt SEGMENT holding chunk c-1 is published by ALL
      // 64 forward blocks (cnt[seg] == 64) — per-segment, race-free.
      if (c > 0){
        const int seg = (c - 1) >> 4;
        while (__hip_atomic_load(&counter[seg], __ATOMIC_ACQUIRE,
                                 __HIP_MEMORY_SCOPE_AGENT) < (unsigned)FWD_BLOCKS)
          __builtin_amdgcn_s_sleep(8);
      }

      float p = (c == 0) ? 0.0f
        : __hip_atomic_load(&ckpt[((size_t)(c - 1) * BB + seq) * 16 + st0],
                            __ATOMIC_RELAXED, __HIP_MEMORY_SCOPE_AGENT);
      const float* yc = y + (size_t)seq * TT + c * CHUNK;
      unsigned lo = 0, hi = 0;

      if (c < NFULL){
        #pragma unroll
        for (int g = 0; g < 16; ++g){
          float4 yv = *(const float4*)(yc + 4*g);
          unsigned d0 = rstep<0>(p, yv.x, EA, r0);
          unsigned d1 = rstep<1>(p, yv.y, EB, r1);
          unsigned d2 = rstep<2>(p, yv.z, EC, r2);
          unsigned d3 = rstep<3>(p, yv.w, ED, r3);
          const int tt = 4 * g;
          if (tt < 32) lo |= (d0 << tt) | (d1 << (tt+1)) | (d2 << (tt+2)) | (d3 << (tt+3));
          else         hi |= (d0 << (tt-32)) | (d1 << (tt-31)) | (d2 << (tt-30)) | (d3 << (tt-29));
        }
      } else {
        float4 yv = *(const float4*)(yc);
        unsigned d0 = rstep<0>(p, yv.x, EA, r0);
        unsigned d1 = rstep<1>(p, yv.y, EB, r1);
        unsigned d2 = rstep<2>(p, yv.z, EC, r2);
        unsigned d3 = rstep<3>(p, yv.w, ED, r3);
        lo = d0 | (d1 << 1) | (d2 << 2) | (d3 << 3);
      }

      // fused traceback (proven): words live in this 16-lane group's regs
      int s = l16;
      unsigned long long pb = 0ull;
      if (c < NFULL){
        #pragma unroll
        for (int j = 63; j >= 0; --j){
          int l = (int)((IPI_TAB[(j + 1) & 3] >> (4 * s)) & 15);
          unsigned hw = __shfl((j >= 32) ? hi : lo, base + l);
          unsigned long long b = (hw >> (j & 31)) & 1;
          s = (s >> 1) | ((int)b << 3);
          pb |= b << j;
        }
      } else {
        #pragma unroll
        for (int j = 3; j >= 0; --j){
          int l = (int)((IPI_TAB[(j + 1) & 3] >> (4 * s)) & 15);
          unsigned hw = __shfl(lo, base + l);
          unsigned long long b = (hw >> j) & 1;
          s = (s >> 1) | ((int)b << 3);
          pb |= b << j;
        }
      }
      bits[(size_t)pair * 16 + l16] = pb;
      map [(size_t)pair * 16 + l16] = (unsigned char)s;
    }
  }
}

// ---------------- K4: compose maps backward -> chunk end states ----------------
__global__ __launch_bounds__(256) void k_compose(const unsigned char* __restrict__ map,
                                                 unsigned char* __restrict__ Earr){
  const int seq = threadIdx.x;
  int s = 0;
  Earr[(size_t)NFULL * BB + seq] = 0;              // end state of tail chunk = 0
  #pragma unroll 8
  for (int c = NC - 1; c >= 1; --c){
    const uint4 mr = *(const uint4*)(map + ((size_t)c * BB + seq) * 16);
    unsigned wsel = (s < 8) ? ((s < 4) ? mr.x : mr.y) : ((s < 12) ? mr.z : mr.w);
    s = (wsel >> ((s & 3) * 8)) & 15;
    Earr[(size_t)(c - 1) * BB + seq] = (unsigned char)s;
  }
}

// ---------------- K5: emit = select hypothesis, expand bits to floats --------
__global__ __launch_bounds__(256) void k_emit(const unsigned long long* __restrict__ bits,
                                              const unsigned char* __restrict__ Earr,
                                              float* __restrict__ out){
  const int gt   = blockIdx.x * 256 + threadIdx.x;
  const int pair = gt >> 4;        // c*256+seq, c < 256
  const int l16  = gt & 15;
  const int c    = pair >> 8;
  const int seq  = pair & 255;
  const int e    = Earr[(size_t)c * BB + seq];             // broadcast in group
  const unsigned long long w = bits[(size_t)pair * 16 + e];// broadcast in group
  const int j0 = l16 * 4;
  float4 f;
  f.x = (float)((w >> (j0    )) & 1);
  f.y = (float)((w >> (j0 + 1)) & 1);
  f.z = (float)((w >> (j0 + 2)) & 1);
  f.w = (float)((w >> (j0 + 3)) & 1);
  *(float4*)(out + (size_t)seq * T_OUT + c * CHUNK + j0) = f;
}

extern "C" void kernel_launch(void* const* d_in, const int* in_sizes, int n_in,
                              void* d_out, int out_size, void* d_ws, size_t ws_size,
                              hipStream_t stream){
  const float* y = (const float*)d_in[0];
  const float* h = (const float*)d_in[1];
  float* out = (float*)d_out;

  const size_t BITS_B = (size_t)NC * BB * 16 * 8;           // 8,421,376
  const size_t MAP_B  = (size_t)NC * BB * 16;               // 1,052,672
  const size_t E_B    = (size_t)NC * BB;                    //    65,792
  const size_t CKPT_B = (size_t)NFULL * BB * 16 * 4;        // 4,194,304
  const size_t CNT_B  = 128;
  if (ws_size < BITS_B + MAP_B + E_B + CKPT_B + CNT_B) return;

  char* ws = (char*)d_ws;
  unsigned long long* bits = (unsigned long long*)ws;
  unsigned char*      map  = (unsigned char*)(ws + BITS_B);
  unsigned char*      Earr = (unsigned char*)(ws + BITS_B + MAP_B);
  float*              ckpt = (float*)(ws + BITS_B + MAP_B + E_B);
  unsigned*           cnt  = (unsigned*)(ws + BITS_B + MAP_B + E_B + CKPT_B);

  hipLaunchKernelGGL(k_zero,    dim3(1),    dim3(1),   0, stream, cnt);
  hipLaunchKernelGGL(k_main,    dim3(FWD_BLOCKS + RPL_BLOCKS), dim3(256), 0, stream,
                     y, h, ckpt, bits, map, cnt);
  hipLaunchKernelGGL(k_compose, dim3(1),    dim3(256), 0, stream, map, Earr);
  hipLaunchKernelGGL(k_emit,    dim3(4096), dim3(256), 0, stream, bits, Earr, out);
}